// Round 11
// baseline (122.181 us; speedup 1.0000x reference)
//
#include <hip/hip_runtime.h>
#include <stdint.h>

#define B_DIM 4096
#define I_DIM 1024
#define O_DIM 1024
#define KD    4096             // i*4 + (k-1): basis col k=0 is identically 0 for x in [0,1)
#define OUT_N (B_DIM * O_DIM)  // 4,194,304

#define SPLITK 4
#define KCHUNK (KD / SPLITK)   // 1024
#define NKT    (KCHUNK / 32)   // 32 K-tiles of 32

typedef short v8s __attribute__((ext_vector_type(8)));
typedef float v4f __attribute__((ext_vector_type(4)));

__device__ __forceinline__ uint16_t f2bf(float f) {
    union { float f; uint32_t u; } v; v.f = f;
    uint32_t u = v.u;
    return (uint16_t)((u + 0x7FFFu + ((u >> 16) & 1u)) >> 16);  // RNE
}
__device__ __forceinline__ float bf2f(uint32_t hi_bits) {
    union { uint32_t u; float f; } v; v.u = hi_bits; return v.f;
}

__device__ __forceinline__ void gload_lds16(const uint16_t* g, uint16_t* l) {
    __builtin_amdgcn_global_load_lds(
        (const __attribute__((address_space(1))) void*)g,
        (__attribute__((address_space(3))) void*)l,
        16, 0, 0);
}

// ---------------- zero d_out (atomic-fallback path only) ----------------
__global__ void zero_kernel(float4* __restrict__ out, int n4) {
    int idx = blockIdx.x * blockDim.x + threadIdx.x;
    if (idx < n4) out[idx] = float4{0.f, 0.f, 0.f, 0.f};
}

// ---------------- fused prep ----------------
// blocks 0..511:   basis  -> A[b][i*4+kk] (8 b-rows x 1024 i per block)
// blocks 512..639: wprep  -> WT[o][i*4+kk] = imp[i,o]*coeffs[i,o,kk+1]
__global__ void prep_kernel(const float* __restrict__ x,
                            const float* __restrict__ coeffs,
                            const float* __restrict__ imp,
                            uint16_t* __restrict__ A, uint16_t* __restrict__ WT) {
    __shared__ __align__(16) char lds[65536];   // used by wprep branch only
    int id = blockIdx.x;
    int t  = threadIdx.x;
    if (id < 512) {
        // ---- basis (closed form, uniform cubic B-spline) ----
        int b0 = id * 8;
#pragma unroll
        for (int bb = 0; bb < 8; ++bb) {
            int b = b0 + bb;
#pragma unroll
            for (int q = 0; q < 4; ++q) {
                int i = q * 256 + t;
                float xv = x[(size_t)b * I_DIM + i];
                float tt = 4.0f * xv;
                float fj = floorf(tt);
                fj = fminf(fmaxf(fj, 0.0f), 3.0f);
                int j4 = (int)fj;
                float u  = tt - fj;
                float um = 1.0f - u;
                float u2 = u * u, u3 = u2 * u;
                const float s = 1.0f / 6.0f;
                float w0 = um * um * um * s;
                float w1 = (3.0f * u3 - 6.0f * u2 + 4.0f) * s;
                float w2 = (-3.0f * u3 + 3.0f * u2 + 3.0f * u + 1.0f) * s;
                float w3 = u3 * s;
                float o0 = (j4 == 0) ? w0 : 0.0f;
                float o1 = (j4 == 0) ? w1 : (j4 == 1) ? w0 : 0.0f;
                float o2 = (j4 == 0) ? w2 : (j4 == 1) ? w1 : (j4 == 2) ? w0 : 0.0f;
                float o3 = (j4 == 0) ? w3 : (j4 == 1) ? w2 : (j4 == 2) ? w1 : w0;
                union { uint16_t h[4]; uint2 v; } pk;
                pk.h[0] = f2bf(o0); pk.h[1] = f2bf(o1);
                pk.h[2] = f2bf(o2); pk.h[3] = f2bf(o3);
                *(uint2*)(A + (size_t)b * KD + (size_t)i * 4) = pk.v;
            }
        }
    } else {
        // ---- wprep with LDS transpose ----
        int bid = id - 512;
        int i0 = (bid & 31) * 32;        // i-slab
        int o0 = (bid >> 5) * 256;       // o-slab
        int o  = o0 + t;
        const int swz = (t & 7) << 4;
        union { uint16_t h[8]; uint4 v; } pk;
#pragma unroll
        for (int ii = 0; ii < 32; ++ii) {
            int i = i0 + ii;
            float im = imp[(size_t)i * O_DIM + o];
            const float* cp = coeffs + ((size_t)i * O_DIM + o) * 5;
            int base = (ii & 1) * 4;
            pk.h[base + 0] = f2bf(im * cp[1]);
            pk.h[base + 1] = f2bf(im * cp[2]);
            pk.h[base + 2] = f2bf(im * cp[3]);
            pk.h[base + 3] = f2bf(im * cp[4]);
            if (ii & 1)
                *(uint4*)(lds + t * 256 + (((ii - 1) * 8) ^ swz)) = pk.v;
        }
        __syncthreads();
#pragma unroll
        for (int j = 0; j < 16; ++j) {
            int c   = t + 256 * j;
            int row = c >> 4;
            int u   = c & 15;
            uint4 v = *(const uint4*)(lds + row * 256 + ((u * 16) ^ ((row & 7) << 4)));
            *(uint4*)(WT + (size_t)(o0 + row) * KD + i0 * 4 + u * 8) = v;
        }
    }
}

// ---------------- GEMM: 128x128 tile, BK=32, splitK=4, 4 blocks/CU ----------------
// LDS: A [128][32], B [128][32] bf16, double-buffered (32 KB total -> 4 blocks/CU).
// 64B rows: XOR-swizzle byte^=(((row>>1)&3)<<4) -> 2-way bank alias (free, m136).
// Inverse-swizzled global source (rule 21).

template<int PARTIAL>
__global__ __launch_bounds__(512, 8)
void gemm_kernel(const uint16_t* __restrict__ A, const uint16_t* __restrict__ WT,
                 float* __restrict__ out, uint16_t* __restrict__ P) {
    // T1: XCD-chunked swizzle; 128 lids/XCD = 4 mt x 4 sk x 8 nt
    int hw  = blockIdx.x;
    int lid = (hw & 7) * 128 + (hw >> 3);
    int nt = lid & 7, sk = (lid >> 3) & 3, mt = lid >> 5;   // nt[0,8) sk[0,4) mt[0,32)

    int t    = threadIdx.x;
    int lane = t & 63;
    int wid  = t >> 6;
    int wr = wid >> 2, wc = wid & 3;           // 2 x 4 wave grid; wave tile 64 x 32

    __shared__ __align__(16) uint16_t smem[16384];   // 32 KB flat
    uint16_t* sA0 = smem;                            // [buf][128][32] -> buf*4096
    uint16_t* sB0 = smem + 8192;

    const uint16_t* Ab = A  + (size_t)(mt * 128) * KD + sk * KCHUNK;
    const uint16_t* Bb = WT + (size_t)(nt * 128) * KD + sk * KCHUNK;

    // staging: thread t -> row r0 = t>>2 (4 thr/row), 16B chunk slot (t&3)
    // inverse swizzle on source k-offset
    const int r0  = t >> 2;                          // [0,128)
    const int kel = ((((t & 3) << 4) ^ (((t >> 3) & 3) << 4)) >> 1);  // elems, 8-aligned

    auto stage = [&](int buf, int kt) {
        const uint16_t* ga = Ab + (size_t)r0 * KD + kt * 32 + kel;
        const uint16_t* gb = Bb + (size_t)r0 * KD + kt * 32 + kel;
        gload_lds16(ga, sA0 + buf * 4096 + t * 8);
        gload_lds16(gb, sB0 + buf * 4096 + t * 8);
    };

    v8s af[4], bf[2];
    v4f acc[4][2] = {};

    const int kb0  = (lane >> 4) << 4;               // k-slot bytes within 64B row
    const int lra  = wr * 64 + (lane & 15);
    const int lrb  = wc * 32 + (lane & 15);
    const int swzA = (((lra >> 1) & 3) << 4);        // (row+16)>>1 &3 invariant per mb
    const int swzB = (((lrb >> 1) & 3) << 4);

    stage(0, 0);
    asm volatile("s_waitcnt vmcnt(0)" ::: "memory");
    __builtin_amdgcn_s_barrier();

#pragma unroll 2
    for (int g = 0; g < NKT; ++g) {
        const int buf = g & 1;
        if (g + 1 < NKT) stage(buf ^ 1, g + 1);

        const char* ba = (const char*)(sA0 + buf * 4096);
        const char* bb = (const char*)(sB0 + buf * 4096);
#pragma unroll
        for (int mb = 0; mb < 4; ++mb)
            af[mb] = *(const v8s*)(ba + (size_t)(lra + mb * 16) * 64 + (kb0 ^ swzA));
#pragma unroll
        for (int nb = 0; nb < 2; ++nb)
            bf[nb] = *(const v8s*)(bb + (size_t)(lrb + nb * 16) * 64 + (kb0 ^ swzB));

        asm volatile("s_waitcnt lgkmcnt(0)" ::: "memory");
        __builtin_amdgcn_s_setprio(1);
#pragma unroll
        for (int mb = 0; mb < 4; ++mb)
#pragma unroll
            for (int nb = 0; nb < 2; ++nb)
                acc[mb][nb] = __builtin_amdgcn_mfma_f32_16x16x32_bf16(af[mb], bf[nb],
                                                                      acc[mb][nb], 0, 0, 0);
        __builtin_amdgcn_s_setprio(0);

        if (g + 1 < NKT) asm volatile("s_waitcnt vmcnt(0)" ::: "memory");
        __builtin_amdgcn_s_barrier();
    }

    // ---- epilogue (C/D layout: col=lane&15, row=(lane>>4)*4+r) ----
    const int oc  = lane & 15;
    const int orr = (lane >> 4) * 4;
    if (PARTIAL) {
        // wave-private LDS transpose [64][32] bf16 (4 KB region), coalesced stores
        uint16_t* wlds = smem + wid * 2048;          // [64 rows][32 cols]
#pragma unroll
        for (int mb = 0; mb < 4; ++mb)
#pragma unroll
            for (int nb = 0; nb < 2; ++nb)
#pragma unroll
                for (int r = 0; r < 4; ++r) {
                    int row = mb * 16 + orr + r;
                    int col = nb * 16 + oc;
                    wlds[row * 32 + (col ^ (((row >> 2) & 3) << 3))] = f2bf(acc[mb][nb][r]);
                }
        asm volatile("s_waitcnt lgkmcnt(0)" ::: "memory");   // wave-private, no barrier
        uint16_t* pb = P + (size_t)sk * OUT_N
                         + (size_t)(mt * 128 + wr * 64) * O_DIM + nt * 128 + wc * 32;
#pragma unroll
        for (int j = 0; j < 4; ++j) {
            int c   = j * 64 + lane;
            int row = c >> 2;
            int u   = (c & 3) * 8;
            uint4 v = *(const uint4*)&wlds[row * 32 + (u ^ (((row >> 2) & 3) << 3))];
            *(uint4*)(pb + (size_t)row * O_DIM + u) = v;
        }
    } else {
        float* ob = out + (size_t)(mt * 128 + wr * 64) * O_DIM + nt * 128 + wc * 32;
#pragma unroll
        for (int mb = 0; mb < 4; ++mb)
#pragma unroll
            for (int nb = 0; nb < 2; ++nb)
#pragma unroll
                for (int r = 0; r < 4; ++r)
                    atomicAdd(&ob[(size_t)(mb * 16 + orr + r) * O_DIM + nb * 16 + oc],
                              acc[mb][nb][r]);
    }
}

// ---------------- reduce: out[j] = sum_sk bf2f(P[sk][j]) ----------------
__global__ void reduce_kernel(const uint16_t* __restrict__ P, float* __restrict__ out) {
    size_t idx = ((size_t)blockIdx.x * 256 + threadIdx.x) * 8;
    float s[8] = {0, 0, 0, 0, 0, 0, 0, 0};
#pragma unroll
    for (int sk = 0; sk < SPLITK; ++sk) {
        uint4 v = *(const uint4*)(P + (size_t)sk * OUT_N + idx);
        uint32_t w[4] = {v.x, v.y, v.z, v.w};
#pragma unroll
        for (int j = 0; j < 4; ++j) {
            s[2 * j]     += bf2f((w[j] & 0xFFFFu) << 16);
            s[2 * j + 1] += bf2f(w[j] & 0xFFFF0000u);
        }
    }
    float4 lo = {s[0], s[1], s[2], s[3]};
    float4 hi = {s[4], s[5], s[6], s[7]};
    *(float4*)(out + idx)     = lo;
    *(float4*)(out + idx + 4) = hi;
}

extern "C" void kernel_launch(void* const* d_in, const int* in_sizes, int n_in,
                              void* d_out, int out_size, void* d_ws, size_t ws_size,
                              hipStream_t stream) {
    const float* x      = (const float*)d_in[0];
    const float* coeffs = (const float*)d_in[1];
    const float* imp    = (const float*)d_in[2];
    float* out = (float*)d_out;

    const size_t A_ELEMS  = (size_t)B_DIM * KD;          // 16,777,216 (33.6 MB)
    const size_t WT_ELEMS = (size_t)O_DIM * KD;          //  4,194,304 ( 8.4 MB)
    const size_t P_ELEMS  = (size_t)SPLITK * OUT_N;      // 16,777,216 (33.6 MB)
    uint16_t* A  = (uint16_t*)d_ws;
    uint16_t* WT = A + A_ELEMS;
    uint16_t* P  = WT + WT_ELEMS;
    const size_t need = (A_ELEMS + WT_ELEMS + P_ELEMS) * 2;   // ~75.5 MB

    hipLaunchKernelGGL(prep_kernel, dim3(512 + 128), dim3(256), 0, stream,
                       x, coeffs, imp, A, WT);
    if (ws_size >= need) {
        hipLaunchKernelGGL((gemm_kernel<1>), dim3(1024), dim3(512), 0, stream, A, WT, out, P);
        hipLaunchKernelGGL(reduce_kernel, dim3(OUT_N / 8 / 256), dim3(256), 0, stream, P, out);
    } else {
        hipLaunchKernelGGL(zero_kernel, dim3((OUT_N / 4) / 256), dim3(256), 0, stream,
                           (float4*)out, OUT_N / 4);
        hipLaunchKernelGGL((gemm_kernel<0>), dim3(1024), dim3(512), 0, stream, A, WT, out, P);
    }
}

// Round 12
// 80.750 us; speedup vs baseline: 1.5131x; 1.5131x over previous
//
#include <hip/hip_runtime.h>
#include <stdint.h>

#define B_DIM 4096
#define I_DIM 1024
#define O_DIM 1024
#define KD    4096             // i*4 + (k-1): basis col k=0 is identically 0 for x in [0,1)
#define OUT_N (B_DIM * O_DIM)  // 4,194,304

#define SPLITK 2
#define KCHUNK (KD / SPLITK)   // 2048
#define NKT    (KCHUNK / 64)   // 32 K-tiles of 64

typedef short v8s __attribute__((ext_vector_type(8)));
typedef float v4f __attribute__((ext_vector_type(4)));

__device__ __forceinline__ uint16_t f2bf(float f) {
    union { float f; uint32_t u; } v; v.f = f;
    uint32_t u = v.u;
    return (uint16_t)((u + 0x7FFFu + ((u >> 16) & 1u)) >> 16);  // RNE
}
__device__ __forceinline__ float bf2f(uint32_t hi_bits) {
    union { uint32_t u; float f; } v; v.u = hi_bits; return v.f;
}

__device__ __forceinline__ void gload_lds16(const uint16_t* g, uint16_t* l) {
    __builtin_amdgcn_global_load_lds(
        (const __attribute__((address_space(1))) void*)g,
        (__attribute__((address_space(3))) void*)l,
        16, 0, 0);
}

// closed-form uniform cubic B-spline: 4 bf16 (kk=0..3) for one x
__device__ __forceinline__ void eval_basis4(float xv, uint16_t* h) {
    float tt = 4.0f * xv;
    float fj = floorf(tt);
    fj = fminf(fmaxf(fj, 0.0f), 3.0f);
    int j4 = (int)fj;
    float u  = tt - fj;
    float um = 1.0f - u;
    float u2 = u * u, u3 = u2 * u;
    const float s = 1.0f / 6.0f;
    float w0 = um * um * um * s;
    float w1 = (3.0f * u3 - 6.0f * u2 + 4.0f) * s;
    float w2 = (-3.0f * u3 + 3.0f * u2 + 3.0f * u + 1.0f) * s;
    float w3 = u3 * s;
    float o0 = (j4 == 0) ? w0 : 0.0f;
    float o1 = (j4 == 0) ? w1 : (j4 == 1) ? w0 : 0.0f;
    float o2 = (j4 == 0) ? w2 : (j4 == 1) ? w1 : (j4 == 2) ? w0 : 0.0f;
    float o3 = (j4 == 0) ? w3 : (j4 == 1) ? w2 : (j4 == 2) ? w1 : w0;
    h[0] = f2bf(o0); h[1] = f2bf(o1); h[2] = f2bf(o2); h[3] = f2bf(o3);
}

// ---------------- zero d_out (atomic-fallback path only) ----------------
__global__ void zero_kernel(float4* __restrict__ out, int n4) {
    int idx = blockIdx.x * blockDim.x + threadIdx.x;
    if (idx < n4) out[idx] = float4{0.f, 0.f, 0.f, 0.f};
}

// ---------------- prep: wprep only (basis now fused into GEMM) ----------------
// 128 blocks: WT[o][i*4+kk] = imp[i,o]*coeffs[i,o,kk+1], LDS transpose, coalesced R+W
__global__ void prep_kernel(const float* __restrict__ coeffs,
                            const float* __restrict__ imp,
                            uint16_t* __restrict__ WT) {
    __shared__ __align__(16) char lds[65536];
    int bid = blockIdx.x;
    int t   = threadIdx.x;
    int i0 = (bid & 31) * 32;        // i-slab
    int o0 = (bid >> 5) * 256;       // o-slab
    int o  = o0 + t;
    const int swz = (t & 7) << 4;
    union { uint16_t h[8]; uint4 v; } pk;
#pragma unroll
    for (int ii = 0; ii < 32; ++ii) {
        int i = i0 + ii;
        float im = imp[(size_t)i * O_DIM + o];
        const float* cp = coeffs + ((size_t)i * O_DIM + o) * 5;
        int base = (ii & 1) * 4;
        pk.h[base + 0] = f2bf(im * cp[1]);
        pk.h[base + 1] = f2bf(im * cp[2]);
        pk.h[base + 2] = f2bf(im * cp[3]);
        pk.h[base + 3] = f2bf(im * cp[4]);
        if (ii & 1)
            *(uint4*)(lds + t * 256 + (((ii - 1) * 8) ^ swz)) = pk.v;
    }
    __syncthreads();
#pragma unroll
    for (int j = 0; j < 16; ++j) {
        int c   = t + 256 * j;
        int row = c >> 4;
        int u   = c & 15;
        uint4 v = *(const uint4*)(lds + row * 256 + ((u * 16) ^ ((row & 7) << 4)));
        *(uint4*)(WT + (size_t)(o0 + row) * KD + i0 * 4 + u * 8) = v;
    }
}

// ---------------- GEMM: 128x128, BK=64, splitK=2, 2 blocks/CU, FUSED basis A ----------------
// LDS: A [128][64], B [128][64] bf16, double-buffered (64 KB).
// A staged by in-register basis compute + swizzled ds_write (rule 21 reg-staging);
// B staged via global_load_lds with inverse-swizzled source.
// Row stride 128B, XOR-swizzle byte^=((row&7)<<4) (T2).

template<int PARTIAL>
__global__ __launch_bounds__(512, 4)
void gemm_kernel(const float* __restrict__ x, const uint16_t* __restrict__ WT,
                 float* __restrict__ out, uint16_t* __restrict__ P) {
    // T1: XCD-chunked swizzle; 64 lids/XCD = 4 mt x 2 sk x 8 nt (panel L2 reuse)
    int hw  = blockIdx.x;
    int lid = (hw & 7) * 64 + (hw >> 3);
    int nt = lid & 7, sk = (lid >> 3) & 1, mt = lid >> 4;   // mt[0,32) nt[0,8) sk[0,2)

    int t    = threadIdx.x;
    int lane = t & 63;
    int wid  = t >> 6;
    int wr = wid >> 2, wc = wid & 3;           // 2 x 4 wave grid; wave tile 64 x 32

    __shared__ __align__(16) uint16_t smem[32768];   // 64 KB flat
    uint16_t* sA0 = smem;                            // [buf][128][64] -> buf*8192
    uint16_t* sB0 = smem + 16384;

    const uint16_t* Bb = WT + (size_t)(nt * 128) * KD + sk * KCHUNK;

    // B staging (identical to round 10): row r0b = t>>3, inverse-swizzled source
    const int r0b = t >> 3;
    const int kel = ((((t & 7) << 4) ^ ((r0b & 7) << 4)) >> 1);
    auto stageB = [&](int buf, int kt) {
        const uint16_t* gb = Bb + (size_t)r0b * KD + kt * 64 + kel;
        gload_lds16(gb,                   sB0 + buf * 8192 + t * 8);
        gload_lds16(gb + (size_t)64 * KD, sB0 + buf * 8192 + 4096 + t * 8);
    };

    // A compute-staging: row ra = t>>2 (b-row), slots 2(t&3), 2(t&3)+1 within 128B row.
    // x float4 covers i = sk*512 + kt*16 + 4(t&3) + {0..3}; chunk c uses elems {2c,2c+1}.
    const int ra  = t >> 2;
    const int swA = (ra & 7) << 4;                   // byte swizzle for this row
    const float* xb = x + (size_t)(mt * 128 + ra) * I_DIM + sk * 512 + 4 * (t & 3);
    uint16_t* aw = sA0 + ra * 64;                    // +buf*8192 at use
    const int off0 = ((2 * (t & 3) * 16) ^ swA) >> 1;        // elems, 16B-aligned
    const int off1 = (((2 * (t & 3) + 1) * 16) ^ swA) >> 1;

    auto stageA = [&](int buf, float4 xq) {
        union { uint16_t h[8]; uint4 v; } c0, c1;
        eval_basis4(xq.x, c0.h); eval_basis4(xq.y, c0.h + 4);
        eval_basis4(xq.z, c1.h); eval_basis4(xq.w, c1.h + 4);
        uint16_t* b = aw + buf * 8192;
        *(uint4*)(b + off0) = c0.v;
        *(uint4*)(b + off1) = c1.v;
    };

    v8s af[4][2], bf[2][2];
    v4f acc[4][2] = {};

    const int swz = (lane & 7) << 4;
    const int kb0 = (lane >> 4) << 4;
    const int lra = wr * 64 + (lane & 15);
    const int lrb = wc * 32 + (lane & 15);

    // ---- prologue: tile 0 ----
    {
        float4 xq = *(const float4*)(xb);            // x(0)
        stageB(0, 0);
        stageA(0, xq);
    }
    asm volatile("s_waitcnt vmcnt(0) lgkmcnt(0)" ::: "memory");
    __builtin_amdgcn_s_barrier();

#pragma unroll 2
    for (int g = 0; g < NKT; ++g) {
        const int buf = g & 1;
        float4 xq;
        if (g + 1 < NKT) {
            xq = *(const float4*)(xb + (g + 1) * 16);   // issue early; used post-MFMA
            stageB(buf ^ 1, g + 1);
        }

        const char* ba = (const char*)(sA0 + buf * 8192);
        const char* bb = (const char*)(sB0 + buf * 8192);
#pragma unroll
        for (int mb = 0; mb < 4; ++mb)
#pragma unroll
            for (int ks = 0; ks < 2; ++ks)
                af[mb][ks] = *(const v8s*)(ba + (size_t)(lra + mb * 16) * 128 + ((kb0 + ks * 64) ^ swz));
#pragma unroll
        for (int nb = 0; nb < 2; ++nb)
#pragma unroll
            for (int ks = 0; ks < 2; ++ks)
                bf[nb][ks] = *(const v8s*)(bb + (size_t)(lrb + nb * 16) * 128 + ((kb0 + ks * 64) ^ swz));

        asm volatile("s_waitcnt lgkmcnt(0)" ::: "memory");
        __builtin_amdgcn_s_setprio(1);
#pragma unroll
        for (int mb = 0; mb < 4; ++mb)
#pragma unroll
            for (int nb = 0; nb < 2; ++nb)
#pragma unroll
                for (int ks = 0; ks < 2; ++ks)
                    acc[mb][nb] = __builtin_amdgcn_mfma_f32_16x16x32_bf16(af[mb][ks], bf[nb][ks],
                                                                          acc[mb][nb], 0, 0, 0);
        __builtin_amdgcn_s_setprio(0);

        if (g + 1 < NKT) stageA(buf ^ 1, xq);        // VALU + 2 ds_write (hidden by co-block MFMA)

        asm volatile("s_waitcnt vmcnt(0) lgkmcnt(0)" ::: "memory");
        __builtin_amdgcn_s_barrier();
    }

    // ---- epilogue (C/D layout: col=lane&15, row=(lane>>4)*4+r) ----
    const int oc  = lane & 15;
    const int orr = (lane >> 4) * 4;
    if (PARTIAL) {
        // wave-private LDS transpose [64][32] bf16 (4 KB region), coalesced stores
        uint16_t* wlds = smem + wid * 2048;
#pragma unroll
        for (int mb = 0; mb < 4; ++mb)
#pragma unroll
            for (int nb = 0; nb < 2; ++nb)
#pragma unroll
                for (int r = 0; r < 4; ++r) {
                    int row = mb * 16 + orr + r;
                    int col = nb * 16 + oc;
                    wlds[row * 32 + (col ^ (((row >> 2) & 3) << 3))] = f2bf(acc[mb][nb][r]);
                }
        asm volatile("s_waitcnt lgkmcnt(0)" ::: "memory");   // wave-private, no barrier
        uint16_t* pb = P + (size_t)sk * OUT_N
                         + (size_t)(mt * 128 + wr * 64) * O_DIM + nt * 128 + wc * 32;
#pragma unroll
        for (int j = 0; j < 4; ++j) {
            int c   = j * 64 + lane;
            int row = c >> 2;
            int u   = (c & 3) * 8;
            uint4 v = *(const uint4*)&wlds[row * 32 + (u ^ (((row >> 2) & 3) << 3))];
            *(uint4*)(pb + (size_t)row * O_DIM + u) = v;
        }
    } else {
        float* ob = out + (size_t)(mt * 128 + wr * 64) * O_DIM + nt * 128 + wc * 32;
#pragma unroll
        for (int mb = 0; mb < 4; ++mb)
#pragma unroll
            for (int nb = 0; nb < 2; ++nb)
#pragma unroll
                for (int r = 0; r < 4; ++r)
                    atomicAdd(&ob[(size_t)(mb * 16 + orr + r) * O_DIM + nb * 16 + oc],
                              acc[mb][nb][r]);
    }
}

// ---------------- reduce: out[j] = sum_sk bf2f(P[sk][j]) ----------------
__global__ void reduce_kernel(const uint16_t* __restrict__ P, float* __restrict__ out) {
    size_t idx = ((size_t)blockIdx.x * 256 + threadIdx.x) * 8;
    float s[8] = {0, 0, 0, 0, 0, 0, 0, 0};
#pragma unroll
    for (int sk = 0; sk < SPLITK; ++sk) {
        uint4 v = *(const uint4*)(P + (size_t)sk * OUT_N + idx);
        uint32_t w[4] = {v.x, v.y, v.z, v.w};
#pragma unroll
        for (int j = 0; j < 4; ++j) {
            s[2 * j]     += bf2f((w[j] & 0xFFFFu) << 16);
            s[2 * j + 1] += bf2f(w[j] & 0xFFFF0000u);
        }
    }
    float4 lo = {s[0], s[1], s[2], s[3]};
    float4 hi = {s[4], s[5], s[6], s[7]};
    *(float4*)(out + idx)     = lo;
    *(float4*)(out + idx + 4) = hi;
}

extern "C" void kernel_launch(void* const* d_in, const int* in_sizes, int n_in,
                              void* d_out, int out_size, void* d_ws, size_t ws_size,
                              hipStream_t stream) {
    const float* x      = (const float*)d_in[0];
    const float* coeffs = (const float*)d_in[1];
    const float* imp    = (const float*)d_in[2];
    float* out = (float*)d_out;

    const size_t WT_ELEMS = (size_t)O_DIM * KD;          //  4,194,304 ( 8.4 MB)
    const size_t P_ELEMS  = (size_t)SPLITK * OUT_N;      //  8,388,608 (16.8 MB)
    uint16_t* WT = (uint16_t*)d_ws;
    uint16_t* P  = WT + WT_ELEMS;
    const size_t need = (WT_ELEMS + P_ELEMS) * 2;        // ~25.2 MB

    hipLaunchKernelGGL(prep_kernel, dim3(128), dim3(256), 0, stream, coeffs, imp, WT);
    if (ws_size >= need) {
        hipLaunchKernelGGL((gemm_kernel<1>), dim3(512), dim3(512), 0, stream, x, WT, out, P);
        hipLaunchKernelGGL(reduce_kernel, dim3(OUT_N / 8 / 256), dim3(256), 0, stream, P, out);
    } else {
        hipLaunchKernelGGL(zero_kernel, dim3((OUT_N / 4) / 256), dim3(256), 0, stream,
                           (float4*)out, OUT_N / 4);
        hipLaunchKernelGGL((gemm_kernel<0>), dim3(512), dim3(512), 0, stream, x, WT, out, P);
    }
}

// Round 13
// 62.948 us; speedup vs baseline: 1.9410x; 1.2828x over previous
//
#include <hip/hip_runtime.h>
#include <stdint.h>

#define B_DIM 4096
#define I_DIM 1024
#define O_DIM 1024
#define KD    4096             // i*4 + (k-1): basis col k=0 is identically 0 for x in [0,1)
#define OUT_N (B_DIM * O_DIM)  // 4,194,304

#define SPLITK 2
#define KCHUNK (KD / SPLITK)   // 2048
#define NKT    (KCHUNK / 64)   // 32 K-tiles of 64

typedef short v8s __attribute__((ext_vector_type(8)));
typedef float v4f __attribute__((ext_vector_type(4)));

__device__ __forceinline__ uint16_t f2bf(float f) {
    union { float f; uint32_t u; } v; v.f = f;
    uint32_t u = v.u;
    return (uint16_t)((u + 0x7FFFu + ((u >> 16) & 1u)) >> 16);  // RNE
}
__device__ __forceinline__ float bf2f(uint32_t hi_bits) {
    union { uint32_t u; float f; } v; v.u = hi_bits; return v.f;
}

__device__ __forceinline__ void gload_lds16(const uint16_t* g, uint16_t* l) {
    __builtin_amdgcn_global_load_lds(
        (const __attribute__((address_space(1))) void*)g,
        (__attribute__((address_space(3))) void*)l,
        16, 0, 0);
}

// ---------------- zero d_out (atomic-fallback path only) ----------------
__global__ void zero_kernel(float4* __restrict__ out, int n4) {
    int idx = blockIdx.x * blockDim.x + threadIdx.x;
    if (idx < n4) out[idx] = float4{0.f, 0.f, 0.f, 0.f};
}

// ---------------- fused prep ----------------
// blocks 0..511:   basis  -> A[b][i*4+kk] (8 b-rows x 1024 i per block)
// blocks 512..639: wprep  -> WT[o][i*4+kk] = imp[i,o]*coeffs[i,o,kk+1]
__global__ void prep_kernel(const float* __restrict__ x,
                            const float* __restrict__ coeffs,
                            const float* __restrict__ imp,
                            uint16_t* __restrict__ A, uint16_t* __restrict__ WT) {
    __shared__ __align__(16) char lds[65536];   // used by wprep branch only
    int id = blockIdx.x;
    int t  = threadIdx.x;
    if (id < 512) {
        // ---- basis (closed form, uniform cubic B-spline) ----
        int b0 = id * 8;
#pragma unroll
        for (int bb = 0; bb < 8; ++bb) {
            int b = b0 + bb;
#pragma unroll
            for (int q = 0; q < 4; ++q) {
                int i = q * 256 + t;
                float xv = x[(size_t)b * I_DIM + i];
                float tt = 4.0f * xv;
                float fj = floorf(tt);
                fj = fminf(fmaxf(fj, 0.0f), 3.0f);
                int j4 = (int)fj;
                float u  = tt - fj;
                float um = 1.0f - u;
                float u2 = u * u, u3 = u2 * u;
                const float s = 1.0f / 6.0f;
                float w0 = um * um * um * s;
                float w1 = (3.0f * u3 - 6.0f * u2 + 4.0f) * s;
                float w2 = (-3.0f * u3 + 3.0f * u2 + 3.0f * u + 1.0f) * s;
                float w3 = u3 * s;
                float o0 = (j4 == 0) ? w0 : 0.0f;
                float o1 = (j4 == 0) ? w1 : (j4 == 1) ? w0 : 0.0f;
                float o2 = (j4 == 0) ? w2 : (j4 == 1) ? w1 : (j4 == 2) ? w0 : 0.0f;
                float o3 = (j4 == 0) ? w3 : (j4 == 1) ? w2 : (j4 == 2) ? w1 : w0;
                union { uint16_t h[4]; uint2 v; } pk;
                pk.h[0] = f2bf(o0); pk.h[1] = f2bf(o1);
                pk.h[2] = f2bf(o2); pk.h[3] = f2bf(o3);
                *(uint2*)(A + (size_t)b * KD + (size_t)i * 4) = pk.v;
            }
        }
    } else {
        // ---- wprep with LDS transpose ----
        int bid = id - 512;
        int i0 = (bid & 31) * 32;        // i-slab
        int o0 = (bid >> 5) * 256;       // o-slab
        int o  = o0 + t;
        const int swz = (t & 7) << 4;
        union { uint16_t h[8]; uint4 v; } pk;
#pragma unroll
        for (int ii = 0; ii < 32; ++ii) {
            int i = i0 + ii;
            float im = imp[(size_t)i * O_DIM + o];
            const float* cp = coeffs + ((size_t)i * O_DIM + o) * 5;
            int base = (ii & 1) * 4;
            pk.h[base + 0] = f2bf(im * cp[1]);
            pk.h[base + 1] = f2bf(im * cp[2]);
            pk.h[base + 2] = f2bf(im * cp[3]);
            pk.h[base + 3] = f2bf(im * cp[4]);
            if (ii & 1)
                *(uint4*)(lds + t * 256 + (((ii - 1) * 8) ^ swz)) = pk.v;
        }
        __syncthreads();
#pragma unroll
        for (int j = 0; j < 16; ++j) {
            int c   = t + 256 * j;
            int row = c >> 4;
            int u   = c & 15;
            uint4 v = *(const uint4*)(lds + row * 256 + ((u * 16) ^ ((row & 7) << 4)));
            *(uint4*)(WT + (size_t)(o0 + row) * KD + i0 * 4 + u * 8) = v;
        }
    }
}

// ---------------- GEMM: 128x128, BK=64, splitK=2, 2 blocks/CU, counted vmcnt ----------------
// LDS: A [2][128][64] + B [3][128][64] bf16 = 80 KB -> 2 blocks/CU.
// 2-phase K-tile: p1 {read k-half0, stage A(g+1)}, p2 {read k-half1, stage B(g+2)};
// boundary vmcnt(2) retires exactly A(g+1)+B(g+1); B(g+2) stays in flight (T4).
// Row stride 128B, XOR-swizzle byte^=((row&7)<<4) (T2), inverse-swizzled source (rule 21).

template<int PARTIAL>
__global__ __launch_bounds__(512, 4)
void gemm_kernel(const uint16_t* __restrict__ A, const uint16_t* __restrict__ WT,
                 float* __restrict__ out, uint16_t* __restrict__ P) {
    // T1: XCD-chunked swizzle; 64 lids/XCD = 4 mt x 2 sk x 8 nt (panel L2 reuse)
    int hw  = blockIdx.x;
    int lid = (hw & 7) * 64 + (hw >> 3);
    int nt = lid & 7, sk = (lid >> 3) & 1, mt = lid >> 4;   // mt[0,32) nt[0,8) sk[0,2)

    int t    = threadIdx.x;
    int lane = t & 63;
    int wid  = t >> 6;
    int wr = wid >> 2, wc = wid & 3;           // 2 x 4 wave grid; wave tile 64 x 32

    __shared__ __align__(16) uint16_t smem[40960];   // 80 KB flat
    uint16_t* sA0 = smem;                            // A: [buf2][128][64] -> buf*8192
    uint16_t* sB0 = smem + 16384;                    // B: [buf3][128][64] -> buf*8192

    const uint16_t* Ab = A  + (size_t)(mt * 128) * KD + sk * KCHUNK;
    const uint16_t* Bb = WT + (size_t)(nt * 128) * KD + sk * KCHUNK;

    const int r0  = t >> 3;                          // [0,64)
    const int kel = ((((t & 7) << 4) ^ ((r0 & 7) << 4)) >> 1);  // elems, 8-aligned

    auto stageA = [&](int buf, int kt) {
        const uint16_t* ga = Ab + (size_t)r0 * KD + kt * 64 + kel;
        gload_lds16(ga,                   sA0 + buf * 8192 + t * 8);
        gload_lds16(ga + (size_t)64 * KD, sA0 + buf * 8192 + 4096 + t * 8);
    };
    auto stageB = [&](int buf, int kt) {
        const uint16_t* gb = Bb + (size_t)r0 * KD + kt * 64 + kel;
        gload_lds16(gb,                   sB0 + buf * 8192 + t * 8);
        gload_lds16(gb + (size_t)64 * KD, sB0 + buf * 8192 + 4096 + t * 8);
    };

    v8s af[4], bf[2];
    v4f acc[4][2] = {};

    const int swz = (lane & 7) << 4;
    const int kb0 = (lane >> 4) << 4;
    const int lra = wr * 64 + (lane & 15);
    const int lrb = wc * 32 + (lane & 15);

    // ---- prologue: queue [B(0)x2, A(0)x2, B(1)x2]; vmcnt(2) retires B0,A0 ----
    stageB(0, 0);
    stageA(0, 0);
    stageB(1, 1);
    asm volatile("s_waitcnt vmcnt(2)" ::: "memory");
    __builtin_amdgcn_s_barrier();

    int bBr = 0;                                   // B read-buf; stage target = (bBr+2)%3
    for (int g = 0; g < NKT; ++g) {
        const int bufA = g & 1;
        const char* ba = (const char*)(sA0 + bufA * 8192);
        const char* bb = (const char*)(sB0 + bBr * 8192);
        const int bBs = bBr >= 1 ? bBr - 1 : 2;    // (bBr+2)%3

        // ---- p1: k-half 0; stage A(g+1) ----
#pragma unroll
        for (int mb = 0; mb < 4; ++mb)
            af[mb] = *(const v8s*)(ba + (size_t)(lra + mb * 16) * 128 + (kb0 ^ swz));
#pragma unroll
        for (int nb = 0; nb < 2; ++nb)
            bf[nb] = *(const v8s*)(bb + (size_t)(lrb + nb * 16) * 128 + (kb0 ^ swz));
        if (g + 1 < NKT) stageA(bufA ^ 1, g + 1);
        __builtin_amdgcn_s_barrier();
        asm volatile("s_waitcnt lgkmcnt(0)" ::: "memory");
        __builtin_amdgcn_s_setprio(1);
#pragma unroll
        for (int mb = 0; mb < 4; ++mb)
#pragma unroll
            for (int nb = 0; nb < 2; ++nb)
                acc[mb][nb] = __builtin_amdgcn_mfma_f32_16x16x32_bf16(af[mb], bf[nb],
                                                                      acc[mb][nb], 0, 0, 0);
        __builtin_amdgcn_s_setprio(0);
        __builtin_amdgcn_s_barrier();

        // ---- p2: k-half 1; stage B(g+2) ----
#pragma unroll
        for (int mb = 0; mb < 4; ++mb)
            af[mb] = *(const v8s*)(ba + (size_t)(lra + mb * 16) * 128 + ((kb0 + 64) ^ swz));
#pragma unroll
        for (int nb = 0; nb < 2; ++nb)
            bf[nb] = *(const v8s*)(bb + (size_t)(lrb + nb * 16) * 128 + ((kb0 + 64) ^ swz));
        if (g + 2 < NKT) stageB(bBs, g + 2);
        __builtin_amdgcn_s_barrier();
        asm volatile("s_waitcnt lgkmcnt(0)" ::: "memory");
        __builtin_amdgcn_s_setprio(1);
#pragma unroll
        for (int mb = 0; mb < 4; ++mb)
#pragma unroll
            for (int nb = 0; nb < 2; ++nb)
                acc[mb][nb] = __builtin_amdgcn_mfma_f32_16x16x32_bf16(af[mb], bf[nb],
                                                                      acc[mb][nb], 0, 0, 0);
        __builtin_amdgcn_s_setprio(0);

        // boundary: queue [B(g+1)2, A(g+1)2, B(g+2)2] -> retire B(g+1),A(g+1); keep B(g+2)
        if (g < NKT - 2)       asm volatile("s_waitcnt vmcnt(2)" ::: "memory");
        else if (g == NKT - 2) asm volatile("s_waitcnt vmcnt(0)" ::: "memory");
        __builtin_amdgcn_s_barrier();

        bBr = bBr == 2 ? 0 : bBr + 1;
    }

    // ---- epilogue (C/D layout: col=lane&15, row=(lane>>4)*4+r) ----
    const int oc  = lane & 15;
    const int orr = (lane >> 4) * 4;
    if (PARTIAL) {
        // wave-private LDS transpose [64][32] bf16 (4 KB region), coalesced stores
        uint16_t* wlds = smem + wid * 2048;
#pragma unroll
        for (int mb = 0; mb < 4; ++mb)
#pragma unroll
            for (int nb = 0; nb < 2; ++nb)
#pragma unroll
                for (int r = 0; r < 4; ++r) {
                    int row = mb * 16 + orr + r;
                    int col = nb * 16 + oc;
                    wlds[row * 32 + (col ^ (((row >> 2) & 3) << 3))] = f2bf(acc[mb][nb][r]);
                }
        asm volatile("s_waitcnt lgkmcnt(0)" ::: "memory");   // wave-private, no barrier
        uint16_t* pb = P + (size_t)sk * OUT_N
                         + (size_t)(mt * 128 + wr * 64) * O_DIM + nt * 128 + wc * 32;
#pragma unroll
        for (int j = 0; j < 4; ++j) {
            int c   = j * 64 + lane;
            int row = c >> 2;
            int u   = (c & 3) * 8;
            uint4 v = *(const uint4*)&wlds[row * 32 + (u ^ (((row >> 2) & 3) << 3))];
            *(uint4*)(pb + (size_t)row * O_DIM + u) = v;
        }
    } else {
        float* ob = out + (size_t)(mt * 128 + wr * 64) * O_DIM + nt * 128 + wc * 32;
#pragma unroll
        for (int mb = 0; mb < 4; ++mb)
#pragma unroll
            for (int nb = 0; nb < 2; ++nb)
#pragma unroll
                for (int r = 0; r < 4; ++r)
                    atomicAdd(&ob[(size_t)(mb * 16 + orr + r) * O_DIM + nb * 16 + oc],
                              acc[mb][nb][r]);
    }
}

// ---------------- reduce: out[j] = sum_sk bf2f(P[sk][j]) ----------------
__global__ void reduce_kernel(const uint16_t* __restrict__ P, float* __restrict__ out) {
    size_t idx = ((size_t)blockIdx.x * 256 + threadIdx.x) * 8;
    float s[8] = {0, 0, 0, 0, 0, 0, 0, 0};
#pragma unroll
    for (int sk = 0; sk < SPLITK; ++sk) {
        uint4 v = *(const uint4*)(P + (size_t)sk * OUT_N + idx);
        uint32_t w[4] = {v.x, v.y, v.z, v.w};
#pragma unroll
        for (int j = 0; j < 4; ++j) {
            s[2 * j]     += bf2f((w[j] & 0xFFFFu) << 16);
            s[2 * j + 1] += bf2f(w[j] & 0xFFFF0000u);
        }
    }
    float4 lo = {s[0], s[1], s[2], s[3]};
    float4 hi = {s[4], s[5], s[6], s[7]};
    *(float4*)(out + idx)     = lo;
    *(float4*)(out + idx + 4) = hi;
}

extern "C" void kernel_launch(void* const* d_in, const int* in_sizes, int n_in,
                              void* d_out, int out_size, void* d_ws, size_t ws_size,
                              hipStream_t stream) {
    const float* x      = (const float*)d_in[0];
    const float* coeffs = (const float*)d_in[1];
    const float* imp    = (const float*)d_in[2];
    float* out = (float*)d_out;

    const size_t A_ELEMS  = (size_t)B_DIM * KD;          // 16,777,216 (33.6 MB)
    const size_t WT_ELEMS = (size_t)O_DIM * KD;          //  4,194,304 ( 8.4 MB)
    const size_t P_ELEMS  = (size_t)SPLITK * OUT_N;      //  8,388,608 (16.8 MB)
    uint16_t* A  = (uint16_t*)d_ws;
    uint16_t* WT = A + A_ELEMS;
    uint16_t* P  = WT + WT_ELEMS;
    const size_t need = (A_ELEMS + WT_ELEMS + P_ELEMS) * 2;   // ~58.7 MB

    hipLaunchKernelGGL(prep_kernel, dim3(512 + 128), dim3(256), 0, stream,
                       x, coeffs, imp, A, WT);
    if (ws_size >= need) {
        hipLaunchKernelGGL((gemm_kernel<1>), dim3(512), dim3(512), 0, stream, A, WT, out, P);
        hipLaunchKernelGGL(reduce_kernel, dim3(OUT_N / 8 / 256), dim3(256), 0, stream, P, out);
    } else {
        hipLaunchKernelGGL(zero_kernel, dim3((OUT_N / 4) / 256), dim3(256), 0, stream,
                           (float4*)out, OUT_N / 4);
        hipLaunchKernelGGL((gemm_kernel<0>), dim3(512), dim3(512), 0, stream, A, WT, out, P);
    }
}

// Round 15
// 59.931 us; speedup vs baseline: 2.0387x; 1.0503x over previous
//
#include <hip/hip_runtime.h>
#include <stdint.h>

#define B_DIM 4096
#define I_DIM 1024
#define O_DIM 1024
#define KD    4096             // i*4 + (k-1): basis col k=0 is identically 0 for x in [0,1)
#define OUT_N (B_DIM * O_DIM)  // 4,194,304

#define SPLITK 2
#define KCHUNK (KD / SPLITK)   // 2048
#define NKT    (KCHUNK / 64)   // 32 K-tiles of 64

typedef short v8s __attribute__((ext_vector_type(8)));
typedef float v4f __attribute__((ext_vector_type(4)));
typedef unsigned int u32x4 __attribute__((ext_vector_type(4)));
typedef float f32x4 __attribute__((ext_vector_type(4)));

__device__ __forceinline__ uint16_t f2bf(float f) {
    union { float f; uint32_t u; } v; v.f = f;
    uint32_t u = v.u;
    return (uint16_t)((u + 0x7FFFu + ((u >> 16) & 1u)) >> 16);  // RNE
}
__device__ __forceinline__ float bf2f(uint32_t hi_bits) {
    union { uint32_t u; float f; } v; v.u = hi_bits; return v.f;
}

__device__ __forceinline__ void gload_lds16(const uint16_t* g, uint16_t* l) {
    __builtin_amdgcn_global_load_lds(
        (const __attribute__((address_space(1))) void*)g,
        (__attribute__((address_space(3))) void*)l,
        16, 0, 0);
}

// ---------------- zero d_out (atomic-fallback path only) ----------------
__global__ void zero_kernel(float4* __restrict__ out, int n4) {
    int idx = blockIdx.x * blockDim.x + threadIdx.x;
    if (idx < n4) out[idx] = float4{0.f, 0.f, 0.f, 0.f};
}

// ---------------- fused prep ----------------
// blocks 0..511:   basis  -> A[b][i*4+kk] (8 b-rows x 1024 i per block)
// blocks 512..639: wprep  -> WT[o][i*4+kk] = imp[i,o]*coeffs[i,o,kk+1]
__global__ void prep_kernel(const float* __restrict__ x,
                            const float* __restrict__ coeffs,
                            const float* __restrict__ imp,
                            uint16_t* __restrict__ A, uint16_t* __restrict__ WT) {
    __shared__ __align__(16) char lds[65536];   // used by wprep branch only
    int id = blockIdx.x;
    int t  = threadIdx.x;
    if (id < 512) {
        // ---- basis (closed form, uniform cubic B-spline) ----
        int b0 = id * 8;
#pragma unroll
        for (int bb = 0; bb < 8; ++bb) {
            int b = b0 + bb;
#pragma unroll
            for (int q = 0; q < 4; ++q) {
                int i = q * 256 + t;
                float xv = x[(size_t)b * I_DIM + i];
                float tt = 4.0f * xv;
                float fj = floorf(tt);
                fj = fminf(fmaxf(fj, 0.0f), 3.0f);
                int j4 = (int)fj;
                float u  = tt - fj;
                float um = 1.0f - u;
                float u2 = u * u, u3 = u2 * u;
                const float s = 1.0f / 6.0f;
                float w0 = um * um * um * s;
                float w1 = (3.0f * u3 - 6.0f * u2 + 4.0f) * s;
                float w2 = (-3.0f * u3 + 3.0f * u2 + 3.0f * u + 1.0f) * s;
                float w3 = u3 * s;
                float o0 = (j4 == 0) ? w0 : 0.0f;
                float o1 = (j4 == 0) ? w1 : (j4 == 1) ? w0 : 0.0f;
                float o2 = (j4 == 0) ? w2 : (j4 == 1) ? w1 : (j4 == 2) ? w0 : 0.0f;
                float o3 = (j4 == 0) ? w3 : (j4 == 1) ? w2 : (j4 == 2) ? w1 : w0;
                union { uint16_t h[4]; uint2 v; } pk;
                pk.h[0] = f2bf(o0); pk.h[1] = f2bf(o1);
                pk.h[2] = f2bf(o2); pk.h[3] = f2bf(o3);
                *(uint2*)(A + (size_t)b * KD + (size_t)i * 4) = pk.v;
            }
        }
    } else {
        // ---- wprep with LDS transpose ----
        int bid = id - 512;
        int i0 = (bid & 31) * 32;        // i-slab
        int o0 = (bid >> 5) * 256;       // o-slab
        int o  = o0 + t;
        const int swz = (t & 7) << 4;
        union { uint16_t h[8]; uint4 v; } pk;
#pragma unroll
        for (int ii = 0; ii < 32; ++ii) {
            int i = i0 + ii;
            float im = imp[(size_t)i * O_DIM + o];
            const float* cp = coeffs + ((size_t)i * O_DIM + o) * 5;
            int base = (ii & 1) * 4;
            pk.h[base + 0] = f2bf(im * cp[1]);
            pk.h[base + 1] = f2bf(im * cp[2]);
            pk.h[base + 2] = f2bf(im * cp[3]);
            pk.h[base + 3] = f2bf(im * cp[4]);
            if (ii & 1)
                *(uint4*)(lds + t * 256 + (((ii - 1) * 8) ^ swz)) = pk.v;
        }
        __syncthreads();
#pragma unroll
        for (int j = 0; j < 16; ++j) {
            int c   = t + 256 * j;
            int row = c >> 4;
            int u   = c & 15;
            uint4 v = *(const uint4*)(lds + row * 256 + ((u * 16) ^ ((row & 7) << 4)));
            *(uint4*)(WT + (size_t)(o0 + row) * KD + i0 * 4 + u * 8) = v;
        }
    }
}

// ---------------- GEMM: 128x128 tile, splitK=2, 2 blocks/CU co-resident ----------------
// LDS: A [128][64], B [128][64] bf16, double-buffered (64 KB -> 2 blocks/CU).
// Row stride 128B, XOR-swizzle byte^=((row&7)<<4) (T2), inverse-swizzled source (rule 21).
// P-partial stores are nontemporal (bypass L2 -> keep A/WT panels resident).

template<int PARTIAL>
__global__ __launch_bounds__(512, 4)
void gemm_kernel(const uint16_t* __restrict__ A, const uint16_t* __restrict__ WT,
                 float* __restrict__ out, uint16_t* __restrict__ P) {
    // T1: XCD-chunked swizzle; each XCD chunk of 64 = 4 mt x 2 sk x 8 nt (panel L2 reuse)
    int hw  = blockIdx.x;
    int lid = (hw & 7) * 64 + (hw >> 3);
    int nt = lid & 7, sk = (lid >> 3) & 1, mt = lid >> 4;   // mt [0,32), nt [0,8), sk [0,2)

    int t    = threadIdx.x;
    int lane = t & 63;
    int wid  = t >> 6;
    int wr = wid >> 2, wc = wid & 3;           // 2 x 4 wave grid; wave tile 64 x 32

    __shared__ __align__(16) uint16_t smem[32768];   // 64 KB flat
    uint16_t* sA0 = smem;                            // [buf][128][64] -> buf*8192
    uint16_t* sB0 = smem + 16384;

    const uint16_t* Ab = A  + (size_t)(mt * 128) * KD + sk * KCHUNK;
    const uint16_t* Bb = WT + (size_t)(nt * 128) * KD + sk * KCHUNK;

    const int r0  = t >> 3;                          // [0,64)
    const int kel = ((((t & 7) << 4) ^ ((r0 & 7) << 4)) >> 1);  // elems, 8-aligned

    auto stage = [&](int buf, int kt) {
        const uint16_t* ga = Ab + (size_t)r0 * KD + kt * 64 + kel;
        const uint16_t* gb = Bb + (size_t)r0 * KD + kt * 64 + kel;
        gload_lds16(ga,                   sA0 + buf * 8192 + t * 8);
        gload_lds16(ga + (size_t)64 * KD, sA0 + buf * 8192 + 4096 + t * 8);
        gload_lds16(gb,                   sB0 + buf * 8192 + t * 8);
        gload_lds16(gb + (size_t)64 * KD, sB0 + buf * 8192 + 4096 + t * 8);
    };

    v8s af[4][2], bf[2][2];
    v4f acc[4][2] = {};

    const int swz = (lane & 7) << 4;
    const int kb0 = (lane >> 4) << 4;
    const int lra = wr * 64 + (lane & 15);
    const int lrb = wc * 32 + (lane & 15);

    stage(0, 0);
    asm volatile("s_waitcnt vmcnt(0)" ::: "memory");
    __builtin_amdgcn_s_barrier();

#pragma unroll 2
    for (int g = 0; g < NKT; ++g) {
        const int buf = g & 1;
        if (g + 1 < NKT) stage(buf ^ 1, g + 1);

        const char* ba = (const char*)(sA0 + buf * 8192);
        const char* bb = (const char*)(sB0 + buf * 8192);
#pragma unroll
        for (int mb = 0; mb < 4; ++mb)
#pragma unroll
            for (int ks = 0; ks < 2; ++ks)
                af[mb][ks] = *(const v8s*)(ba + (size_t)(lra + mb * 16) * 128 + ((kb0 + ks * 64) ^ swz));
#pragma unroll
        for (int nb = 0; nb < 2; ++nb)
#pragma unroll
            for (int ks = 0; ks < 2; ++ks)
                bf[nb][ks] = *(const v8s*)(bb + (size_t)(lrb + nb * 16) * 128 + ((kb0 + ks * 64) ^ swz));

        asm volatile("s_waitcnt lgkmcnt(0)" ::: "memory");
        __builtin_amdgcn_s_setprio(1);
#pragma unroll
        for (int mb = 0; mb < 4; ++mb)
#pragma unroll
            for (int nb = 0; nb < 2; ++nb)
#pragma unroll
                for (int ks = 0; ks < 2; ++ks)
                    acc[mb][nb] = __builtin_amdgcn_mfma_f32_16x16x32_bf16(af[mb][ks], bf[nb][ks],
                                                                          acc[mb][nb], 0, 0, 0);
        __builtin_amdgcn_s_setprio(0);

        if (g + 1 < NKT) asm volatile("s_waitcnt vmcnt(0)" ::: "memory");
        __builtin_amdgcn_s_barrier();
    }

    // ---- epilogue (C/D layout: col=lane&15, row=(lane>>4)*4+r) ----
    const int oc  = lane & 15;
    const int orr = (lane >> 4) * 4;
    if (PARTIAL) {
        // wave-private LDS transpose [64][32] bf16 (4 KB region), coalesced NT stores
        uint16_t* wlds = smem + wid * 2048;          // [64 rows][32 cols]
#pragma unroll
        for (int mb = 0; mb < 4; ++mb)
#pragma unroll
            for (int nb = 0; nb < 2; ++nb)
#pragma unroll
                for (int r = 0; r < 4; ++r) {
                    int row = mb * 16 + orr + r;
                    int col = nb * 16 + oc;
                    wlds[row * 32 + (col ^ (((row >> 2) & 3) << 3))] = f2bf(acc[mb][nb][r]);
                }
        asm volatile("s_waitcnt lgkmcnt(0)" ::: "memory");   // wave-private, no barrier
        uint16_t* pb = P + (size_t)sk * OUT_N
                         + (size_t)(mt * 128 + wr * 64) * O_DIM + nt * 128 + wc * 32;
#pragma unroll
        for (int j = 0; j < 4; ++j) {
            int c   = j * 64 + lane;
            int row = c >> 2;
            int u   = (c & 3) * 8;
            u32x4 v = *(const u32x4*)&wlds[row * 32 + (u ^ (((row >> 2) & 3) << 3))];
            __builtin_nontemporal_store(v, (u32x4*)(pb + (size_t)row * O_DIM + u));
        }
    } else {
        float* ob = out + (size_t)(mt * 128 + wr * 64) * O_DIM + nt * 128 + wc * 32;
#pragma unroll
        for (int mb = 0; mb < 4; ++mb)
#pragma unroll
            for (int nb = 0; nb < 2; ++nb)
#pragma unroll
                for (int r = 0; r < 4; ++r)
                    atomicAdd(&ob[(size_t)(mb * 16 + orr + r) * O_DIM + nb * 16 + oc],
                              acc[mb][nb][r]);
    }
}

// ---------------- reduce: out[j] = sum_sk bf2f(P[sk][j]); NT out-stores ----------------
__global__ void reduce_kernel(const uint16_t* __restrict__ P, float* __restrict__ out) {
    size_t idx = ((size_t)blockIdx.x * 256 + threadIdx.x) * 8;
    float s[8] = {0, 0, 0, 0, 0, 0, 0, 0};
#pragma unroll
    for (int sk = 0; sk < SPLITK; ++sk) {
        uint4 v = *(const uint4*)(P + (size_t)sk * OUT_N + idx);
        uint32_t w[4] = {v.x, v.y, v.z, v.w};
#pragma unroll
        for (int j = 0; j < 4; ++j) {
            s[2 * j]     += bf2f((w[j] & 0xFFFFu) << 16);
            s[2 * j + 1] += bf2f(w[j] & 0xFFFF0000u);
        }
    }
    f32x4 lo = {s[0], s[1], s[2], s[3]};
    f32x4 hi = {s[4], s[5], s[6], s[7]};
    __builtin_nontemporal_store(lo, (f32x4*)(out + idx));
    __builtin_nontemporal_store(hi, (f32x4*)(out + idx + 4));
}

extern "C" void kernel_launch(void* const* d_in, const int* in_sizes, int n_in,
                              void* d_out, int out_size, void* d_ws, size_t ws_size,
                              hipStream_t stream) {
    const float* x      = (const float*)d_in[0];
    const float* coeffs = (const float*)d_in[1];
    const float* imp    = (const float*)d_in[2];
    float* out = (float*)d_out;

    const size_t A_ELEMS  = (size_t)B_DIM * KD;          // 16,777,216 (33.6 MB)
    const size_t WT_ELEMS = (size_t)O_DIM * KD;          //  4,194,304 ( 8.4 MB)
    const size_t P_ELEMS  = (size_t)SPLITK * OUT_N;      //  8,388,608 (16.8 MB)
    uint16_t* A  = (uint16_t*)d_ws;
    uint16_t* WT = A + A_ELEMS;
    uint16_t* P  = WT + WT_ELEMS;
    const size_t need = (A_ELEMS + WT_ELEMS + P_ELEMS) * 2;   // ~58.7 MB

    hipLaunchKernelGGL(prep_kernel, dim3(512 + 128), dim3(256), 0, stream,
                       x, coeffs, imp, A, WT);
    if (ws_size >= need) {
        hipLaunchKernelGGL((gemm_kernel<1>), dim3(512), dim3(512), 0, stream, A, WT, out, P);
        hipLaunchKernelGGL(reduce_kernel, dim3(OUT_N / 8 / 256), dim3(256), 0, stream, P, out);
    } else {
        hipLaunchKernelGGL(zero_kernel, dim3((OUT_N / 4) / 256), dim3(256), 0, stream,
                           (float4*)out, OUT_N / 4);
        hipLaunchKernelGGL((gemm_kernel<0>), dim3(512), dim3(512), 0, stream, A, WT, out, P);
    }
}